// Round 15
// baseline (693.249 us; speedup 1.0000x reference)
//
#include <hip/hip_runtime.h>
#include <math.h>

#define T_DIM 16384
#define A_DIM 128
#define K_DIM 128
#define N_STEPS 16
#define E_DIM 126
#define NSEQ 4

// step0: 512 blocks = 4 seq x 8 atile16 x 16 trange1024; each block: 16 waves,
// wave = 8 atoms x 128 t task -> atomicMax into per-seq 128-entry tile table.
#define NB_STEP0 512
#define NB_TOTAL (NB_STEP0 + NSEQ + 1)

#define SM_U64 8416   // 67.3 KB union arena (solo role is the max)

// order-preserving pack: bigger u64 == (bigger value, then smaller flat idx).
// Never 0 for finite fm values -> 0 doubles as "empty" sentinel.
__device__ inline unsigned long long pack_vi(float v, int fi) {
    unsigned int b = __float_as_uint(v);
    b = (b & 0x80000000u) ? ~b : (b | 0x80000000u);
    return ((unsigned long long)b << 32) | (unsigned int)(~fi);
}
__device__ inline void unpack_vi(unsigned long long p, float* v, int* fi) {
    unsigned int lo = (unsigned int)(p & 0xffffffffu);
    unsigned int b = (unsigned int)(p >> 32);
    unsigned int fb = (b & 0x80000000u) ? (b & 0x7fffffffu) : ~b;
    *v = __uint_as_float(fb);
    *fi = (int)(~lo);
}
__device__ inline unsigned long long u64max(unsigned long long a, unsigned long long b) {
    return a > b ? a : b;
}

// ---------------------------------------------------------------------------
// blocks 0..127: d_unit rows; block 128: zero pmaxG + cnt + done
__global__ __launch_bounds__(256) void k_prep(
    const float* __restrict__ d, float* __restrict__ du,
    unsigned long long* __restrict__ pmaxG, int* __restrict__ ctrl) {
    int blk = blockIdx.x, tid = threadIdx.x;
    if (blk < 128) {
        __shared__ float s[128];
        float v = 0.0f;
        if (tid < 128) { v = d[blk * K_DIM + tid]; s[tid] = v * v; }
        __syncthreads();
        for (int off = 64; off > 0; off >>= 1) {
            if (tid < off) s[tid] += s[tid + off];
            __syncthreads();
        }
        if (tid < 128) du[blk * K_DIM + tid] = v / (sqrtf(s[0]) + 1e-8f);
    } else {
        if (tid < NSEQ * 128) pmaxG[tid] = 0ULL;
        if (tid < NSEQ) ctrl[tid] = 0;          // cnt
        if (tid == NSEQ) ctrl[4] = 0;           // done
    }
}

// ---------------------------------------------------------------------------
// 8 atoms x 128 t task. lane owns t = tglob + 2*lane (+j, j=0,1).
// du: wave-uniform s_load float4; res: sliding window fed by aligned float2
// LDS loads (stride-8B across lanes: 2-way bank aliasing = free).
// Per-acc FMA chain = k ascending, operands identical to prior rounds ->
// bit-identical fm. Returns packed wave max in lane 0.
template <bool CLAMP>
__device__ inline unsigned long long task8x128(
    const float* __restrict__ duP, const float* __restrict__ rsh,
    int off0, int a0, int tglob, int lane) {

    float acc[8][2];
    #pragma unroll
    for (int i = 0; i < 8; i++) { acc[i][0] = 0.0f; acc[i][1] = 0.0f; }

    float r[8];
    if (CLAMP) {
        #pragma unroll
        for (int m = 0; m < 8; m++) {
            unsigned u = (unsigned)(off0 + m);
            float v = rsh[u & (T_DIM - 1)];
            r[m] = (u < (unsigned)T_DIM) ? v : 0.0f;
        }
    } else {
        *(float2*)&r[0] = *(const float2*)&rsh[off0 + 0];
        *(float2*)&r[2] = *(const float2*)&rsh[off0 + 2];
        *(float2*)&r[4] = *(const float2*)&rsh[off0 + 4];
        *(float2*)&r[6] = *(const float2*)&rsh[off0 + 6];
    }

    #pragma unroll 4
    for (int k = 0; k < K_DIM; k += 4) {
        float dA[8][4];
        #pragma unroll
        for (int i = 0; i < 8; i++)
            *(float4*)dA[i] = *(const float4*)(duP + i * K_DIM + k);  // uniform
        #pragma unroll
        for (int dk = 0; dk < 4; dk++) {
            #pragma unroll
            for (int i = 0; i < 8; i++) {
                float s = dA[i][dk];
                acc[i][0] = fmaf(s, r[dk],     acc[i][0]);   // k ascending
                acc[i][1] = fmaf(s, r[dk + 1], acc[i][1]);
            }
        }
        r[0] = r[4]; r[1] = r[5]; r[2] = r[6]; r[3] = r[7];
        if (CLAMP) {
            #pragma unroll
            for (int m = 0; m < 4; m++) {
                unsigned u = (unsigned)(off0 + k + 8 + m);
                float v = rsh[u & (T_DIM - 1)];
                r[4 + m] = (u < (unsigned)T_DIM) ? v : 0.0f;
            }
        } else {
            *(float2*)&r[4] = *(const float2*)&rsh[off0 + k + 8];
            *(float2*)&r[6] = *(const float2*)&rsh[off0 + k + 10];
        }
    }

    float bv = -INFINITY;
    int bi = 0x7fffffff;
    #pragma unroll
    for (int i = 0; i < 8; i++) {           // ascending flat index scan
        #pragma unroll
        for (int j = 0; j < 2; j++) {
            int fi = (a0 + i) * T_DIM + tglob + 2 * lane + j;
            float v = acc[i][j];
            if (v > bv || (v == bv && fi < bi)) { bv = v; bi = fi; }
        }
    }
    #pragma unroll
    for (int off = 32; off > 0; off >>= 1) {
        float v2 = __shfl_down(bv, off);
        int   i2 = __shfl_down(bi, off);
        if (v2 > bv || (v2 == bv && i2 < bi)) { bv = v2; bi = i2; }
    }
    return pack_vi(bv, bi);   // valid in lane 0
}

// ---------------------------------------------------------------------------
__global__ __launch_bounds__(1024, 4) void k_mega(
    const float* __restrict__ a, const float* __restrict__ b,
    const float* __restrict__ du, const float* __restrict__ ae,
    const float* __restrict__ proj, float* __restrict__ emb,
    unsigned long long* __restrict__ pmaxG, int* __restrict__ ctrl,
    float* __restrict__ normsG, float* __restrict__ out) {

    __shared__ unsigned long long SMEM[SM_U64];
    int* cnt  = ctrl;
    int* done = ctrl + 4;
    int blk = blockIdx.x;
    int tid = threadIdx.x;

    if (blk < NB_STEP0) {
        // ===================== step0 =====================
        int seq = blk >> 7;
        int sub = blk & 127;
        int A16 = sub >> 4;           // 0..7
        int R   = sub & 15;           // 0..15
        int tblk = R << 10;
        float* win = (float*)SMEM;    // 1160 floats

        const float* x = (seq < 2 ? a : b) + (seq & 1) * T_DIM;
        for (int i = tid; i < 1160; i += 1024) {
            int t = tblk - 64 + i;
            win[i] = (i < 1151 && t >= 0 && t < T_DIM) ? x[t] : 0.0f;
        }
        __syncthreads();

        int w = tid >> 6, lane = tid & 63;
        int a0 = __builtin_amdgcn_readfirstlane(A16 * 16 + (w & 1) * 8);
        int sT = __builtin_amdgcn_readfirstlane(w >> 1);
        int tglob = tblk + (sT << 7);
        int off0 = (tglob - tblk) + 2 * lane;    // win idx of res[tglob-64+2*lane]
        unsigned long long c = task8x128<false>(du + a0 * K_DIM, win, off0,
                                                a0, tglob, lane);
        if (lane == 0) atomicMax(&pmaxG[seq * 128 + (tglob >> 7)], c);
        __syncthreads();   // compiler drains vmem before barrier -> maxes done
        if (tid == 0) atomicAdd(&cnt[seq], 1);
        return;
    }

    if (blk < NB_STEP0 + NSEQ) {
        // ===================== solo (one block per seq) =====================
        int seq = blk - NB_STEP0;
        float* resL = (float*)SMEM;                     // 16384 f = 64 KB
        unsigned long long* table = SMEM + 8192;        // 128
        unsigned long long* stage = SMEM + 8320;        // 48 used
        unsigned long long* red   = SMEM + 8384;        // 4 (+ floats reuse)
        unsigned long long* wbc   = SMEM + 8400;
        float* fred = (float*)(SMEM + 8384);            // 16 floats for norm

        const float* x = (seq < 2 ? a : b) + (seq & 1) * T_DIM;
        for (int i = tid * 4; i < T_DIM; i += 4096)
            *(float4*)&resL[i] = *(const float4*)&x[i];

        if (tid == 0) {
            while (__hip_atomic_load(&cnt[seq], __ATOMIC_RELAXED,
                                     __HIP_MEMORY_SCOPE_AGENT) < 128)
                __builtin_amdgcn_s_sleep(2);
        }
        __syncthreads();
        __threadfence();   // acquire: pmaxG atomics visible
        if (tid < 128) table[tid] = pmaxG[seq * 128 + tid];
        __syncthreads();

        int lo = 0, hi = 0;
        for (int step = 0; step < N_STEPS; step++) {
            if (step > 0) {
                int Ta = lo >> 7, Tb = (hi - 1) >> 7;
                int ntile = Tb - Ta + 1;             // 1..3
                int ntask = ntile << 4;
                int w = tid >> 6, lane = tid & 63;
                for (int task = w; task < ntask; task += 16) {
                    int tI = __builtin_amdgcn_readfirstlane(task);
                    int a0 = (tI & 15) << 3;
                    int tg = (Ta + (tI >> 4)) << 7;
                    int off0 = tg - 64 + 2 * lane;
                    unsigned long long c;
                    if (tg == 0 || tg == T_DIM - 128)
                        c = task8x128<true>(du + a0 * K_DIM, resL, off0, a0, tg, lane);
                    else
                        c = task8x128<false>(du + a0 * K_DIM, resL, off0, a0, tg, lane);
                    if (lane == 0) stage[tI] = c;
                }
                __syncthreads();
                if (tid < ntile) {
                    unsigned long long m2 = stage[tid << 4];
                    #pragma unroll
                    for (int j = 1; j < 16; j++) m2 = u64max(m2, stage[(tid << 4) + j]);
                    table[Ta + tid] = m2;
                }
                __syncthreads();
            }
            // winner = max over 128-entry table (2 waves, u64 shfl)
            if (tid < 128) {
                unsigned long long m = table[tid];
                #pragma unroll
                for (int off = 32; off > 0; off >>= 1) {
                    unsigned long long o = __shfl_down(m, off);
                    if (o > m) m = o;
                }
                if ((tid & 63) == 0) red[tid >> 6] = m;
            }
            __syncthreads();
            if (tid == 0) wbc[0] = u64max(red[0], red[1]);
            __syncthreads();

            float value; int fi;
            unpack_vi(wbc[0], &value, &fi);
            int ti = fi & (T_DIM - 1);
            int ai = fi >> 14;
            int pos_idx = value > 0.0f ? ti : 0;
            int atom_idx = value > 0.0f ? ai : 0;
            float* e = emb + (seq * N_STEPS + step) * 128;
            if (tid == 0) {
                e[0] = ((float)pos_idx / (float)(T_DIM - 1)) * 20.0f;
                e[1] = value;
            }
            if (tid >= 2 && tid < 128) e[tid] = ae[atom_idx * E_DIM + tid - 2];
            if (tid < 128) {       // apply (mul-then-sub, identical arithmetic)
                int t = ti - K_DIM / 2 + tid;
                if (t >= 0 && t < T_DIM)
                    resL[t] = __fsub_rn(resL[t], __fmul_rn(value, du[ai * K_DIM + tid]));
            }
            lo = ti - (K_DIM - 1); if (lo < 0) lo = 0;
            hi = ti + K_DIM;       if (hi > T_DIM) hi = T_DIM;
            __syncthreads();
        }

        // norm over LDS residual
        {
            float s = 0.0f;
            for (int i = tid; i < T_DIM; i += 1024) {
                float v = resL[i];
                s = fmaf(v, v, s);
            }
            #pragma unroll
            for (int off = 32; off > 0; off >>= 1) s += __shfl_down(s, off);
            if ((tid & 63) == 0) fred[tid >> 6] = s;
            __syncthreads();
            if (tid == 0) {
                float t2 = 0.0f;
                for (int j = 0; j < 16; j++) t2 += fred[j];
                normsG[seq] = sqrtf(t2);
                __threadfence();
                atomicAdd(done, 1);
            }
        }
        return;
    }

    // ===================== tail =====================
    {
        float* keys  = (float*)SMEM;               // 64
        int*   order = (int*)(SMEM + 32);          // 64
        float* sh    = (float*)(SMEM + 64);        // 1024
        float* norms = (float*)(SMEM + 576);       // 4

        if (tid == 0) {
            while (__hip_atomic_load(done, __ATOMIC_RELAXED,
                                     __HIP_MEMORY_SCOPE_AGENT) < NSEQ)
                __builtin_amdgcn_s_sleep(8);
        }
        __syncthreads();
        __threadfence();   // acquire: emb + norms

        if (tid < NSEQ) norms[tid] = normsG[tid];
        if (tid < 64) {
            int seq = tid >> 4, st = tid & 15;
            const float* e = emb + (seq * N_STEPS + st) * 128;
            float kk = 0.0f;
            for (int dd = 0; dd < 128; dd++) kk = fmaf(e[dd], proj[dd], kk);
            keys[tid] = kk;
        }
        __syncthreads();
        if (tid < NSEQ) {
            int ord[N_STEPS];
            for (int i = 0; i < N_STEPS; i++) ord[i] = i;
            for (int i = 1; i < N_STEPS; i++) {     // stable ascending
                int oi = ord[i];
                float kv = keys[tid * N_STEPS + oi];
                int j = i - 1;
                while (j >= 0 && keys[tid * N_STEPS + ord[j]] > kv) {
                    ord[j + 1] = ord[j]; j--;
                }
                ord[j + 1] = oi;
            }
            for (int i = 0; i < N_STEPS; i++) order[tid * N_STEPS + i] = ord[i];
        }
        __syncthreads();
        float s = 0.0f;
        #pragma unroll
        for (int t = 0; t < 4; t++) {
            int idx = tid + t * 1024;
            int bq = idx >> 11;
            int st = (idx >> 7) & 15;
            int dd = idx & 127;
            float va = emb[((bq    ) * N_STEPS + order[bq * N_STEPS + st]) * 128 + dd];
            float vb = emb[((2 + bq) * N_STEPS + order[(2 + bq) * N_STEPS + st]) * 128 + dd];
            float df = va - vb;
            s = fmaf(df, df, s);
        }
        sh[tid] = s;
        __syncthreads();
        for (int off = 512; off > 0; off >>= 1) {
            if (tid < off) sh[tid] += sh[tid + off];
            __syncthreads();
        }
        if (tid == 0) {
            float mse = sh[0] / 4096.0f;
            float mad = 0.5f * (fabsf(norms[0] - norms[2]) + fabsf(norms[1] - norms[3]));
            out[0] = mse + mad;
        }
    }
}

// ---------------------------------------------------------------------------
extern "C" void kernel_launch(void* const* d_in, const int* in_sizes, int n_in,
                              void* d_out, int out_size, void* d_ws, size_t ws_size,
                              hipStream_t stream) {
    const float* a    = (const float*)d_in[0];
    const float* b    = (const float*)d_in[1];
    const float* d    = (const float*)d_in[2];
    const float* ae   = (const float*)d_in[3];
    const float* proj = (const float*)d_in[4];
    float* out = (float*)d_out;

    float* ws  = (float*)d_ws;
    float* du  = ws;                              // 16384 f
    float* emb = du + A_DIM * K_DIM;              // 8192 f
    unsigned long long* pmaxG = (unsigned long long*)(emb + NSEQ * N_STEPS * 128); // 512 u64
    int*   ctrl   = (int*)(pmaxG + NSEQ * 128);   // cnt[4], done[1] (+pad)
    float* normsG = (float*)(ctrl + 8);           // 4 f

    k_prep<<<129, 256, 0, stream>>>(d, du, pmaxG, ctrl);
    k_mega<<<NB_TOTAL, 1024, 0, stream>>>(a, b, du, ae, proj, emb, pmaxG,
                                          ctrl, normsG, out);
}